// Round 1
// baseline (122.532 us; speedup 1.0000x reference)
//
#include <hip/hip_runtime.h>
#include <hip/hip_bf16.h>
#include <stdint.h>

typedef unsigned int uint32;
typedef unsigned short u16;
typedef __attribute__((ext_vector_type(8))) short bf16x8;
typedef __attribute__((ext_vector_type(4))) float f32x4;

// problem sizes
#define BB 8192
#define NN 512
#define ON 256
// ws float-offsets
#define WS_SCALE 0
#define WS_SHIFT 512
#define WS_SUBQ  1024           // 6*512 floats (sub[0]=0)
#define WS_PSUM  4096           // 128*512
#define WS_PSQ   (4096+65536)
// ws byte offsets
#define WRT_OFF  (1u<<20)       // 64 chunks * 16384 bf16 = 2 MB
#define AMIN_OFF (4u<<20)       // 8192*1024 bf16 = 16 MB

__device__ __forceinline__ u16 f2bf(float f){
  uint32 u; __builtin_memcpy(&u,&f,4);
  u = u + 0x7fffu + ((u>>16)&1u);
  return (u16)(u>>16);
}
__device__ __forceinline__ float bf2f(u16 b){
  uint32 u = ((uint32)b)<<16; float f; __builtin_memcpy(&f,&u,4); return f;
}
__device__ __forceinline__ uint32 pk2(float a, float b){
  return (uint32)f2bf(a) | ((uint32)f2bf(b)<<16);
}
__device__ __forceinline__ float plo(uint32 p){ uint32 u=p<<16; float f; __builtin_memcpy(&f,&u,4); return f; }
__device__ __forceinline__ float phi(uint32 p){ uint32 u=p&0xffff0000u; float f; __builtin_memcpy(&f,&u,4); return f; }

// ---------------- stats: partial column sums ----------------
__global__ __launch_bounds__(512) void k_stats_partial(const float* __restrict__ x,
                                                       float* __restrict__ ws){
  int s = blockIdx.x;          // 128 blocks, 64 rows each
  int n = threadIdx.x;         // 512 threads = columns
  const float* xp = x + (size_t)s*64*NN + n;
  float sum = 0.f, sq = 0.f;
  #pragma unroll 8
  for (int r=0; r<64; ++r){ float v = xp[(size_t)r*NN]; sum += v; sq += v*v; }
  ws[WS_PSUM + s*NN + n] = sum;
  ws[WS_PSQ  + s*NN + n] = sq;
}

// ---------------- stats: finalize ----------------
__global__ __launch_bounds__(512) void k_stats_final(const float* __restrict__ beta,
                                                     const float* __restrict__ gamma,
                                                     float* __restrict__ ws){
  int n = threadIdx.x;         // 512 threads, 1 block
  float sum = 0.f, sq = 0.f;
  for (int s=0; s<128; ++s){ sum += ws[WS_PSUM + s*NN + n]; sq += ws[WS_PSQ + s*NN + n]; }
  float mean = sum * (1.0f/8192.0f);
  float var  = sq  * (1.0f/8192.0f) - mean*mean;
  float g = gamma[n], b = beta[n];
  float inv = 1.0f / sqrtf(var + 0.001f);
  float scale = g * inv;
  float shift = b - mean*scale;
  ws[WS_SCALE + n] = scale;
  ws[WS_SHIFT + n] = shift;
  const float QC[5] = {-3.0f, -0.834f, -0.248f, 0.248f, 0.834f};
  ws[WS_SUBQ + 0*NN + n] = 0.f;
  #pragma unroll
  for (int c=0; c<5; ++c)
    ws[WS_SUBQ + (c+1)*NN + n] = (QC[c]*var + mean)*g - b;
}

// ---------------- w reorder: k' = q*512+n (then min rows), [o][k] per chunk, bf16, swizzled ----------------
__global__ __launch_bounds__(256) void k_prep_w(const float* __restrict__ w,
                                                u16* __restrict__ wrT){
  int c = blockIdx.x;          // 64 K-chunks of 64
  int o = threadIdx.x;         // 256 output cols
  int swz = o & 7;
  u16* dst = wrT + c*16384 + o*64;
  #pragma unroll
  for (int g=0; g<8; ++g){
    union { bf16x8 v; u16 h[8]; } R;
    #pragma unroll
    for (int i=0; i<8; ++i){
      int k = g*8 + i;
      int sk;
      if (c < 48){ int q = c>>3; int n = (c&7)*64 + k; sk = n*6 + q; }
      else       { sk = 3072 + (c-48)*64 + k; }
      R.h[i] = f2bf(w[(size_t)sk*ON + o]);
    }
    *(bf16x8*)(dst + ((g ^ swz)*8)) = R.v;
  }
}

// ---------------- min-feature matrix A'' (8192 x 1024 bf16) ----------------
__global__ __launch_bounds__(256) void k_minfeat(const float* __restrict__ x,
                                                 const float* __restrict__ ws,
                                                 const int* __restrict__ ci,
                                                 u16* __restrict__ amin){
  __shared__ u16 nrm[NN];
  int b = blockIdx.x;          // 8192 rows
  int t = threadIdx.x;         // 256
  {
    float2 v  = ((const float2*)(x + (size_t)b*NN))[t];
    float2 sc = ((const float2*)(ws + WS_SCALE))[t];
    float2 sh = ((const float2*)(ws + WS_SHIFT))[t];
    float z0 = fmaf(v.x, sc.x, sh.x);
    float z1 = fmaf(v.y, sc.y, sh.y);
    ((uint32*)nrm)[t] = pk2(z0, z1);
  }
  __syncthreads();
  int m0 = t*4;
  uint32 lo, hi;
  {
    float r[4];
    #pragma unroll
    for (int i=0; i<4; ++i){
      int m = m0 + i;
      int n1 = ci[m*5+1], q1 = ci[m*5+2], n2 = ci[m*5+3], q2 = ci[m*5+4];
      float v1 = fmaxf(bf2f(nrm[n1]) - ws[WS_SUBQ + q1*NN + n1], 0.f);
      float v2 = fmaxf(bf2f(nrm[n2]) - ws[WS_SUBQ + q2*NN + n2], 0.f);
      r[i] = fminf(v1, v2);
    }
    lo = pk2(r[0], r[1]); hi = pk2(r[2], r[3]);
  }
  uint32* dst = (uint32*)(amin + (size_t)b*1024 + m0);
  dst[0] = lo; dst[1] = hi;
}

// ---------------- fused feature-GEMM ----------------
// grid 256: rowtile = bx>>1 (64 rows), coltile = bx&1 (128 cols). 512 threads = 8 waves (2M x 4N).
__global__ __launch_bounds__(512) void k_gemm(const float* __restrict__ x,
                                              const float* __restrict__ ws,
                                              const u16* __restrict__ wrT,
                                              const u16* __restrict__ amin,
                                              const float* __restrict__ biases,
                                              float* __restrict__ out){
  __shared__ float subq[6*NN];     // 12 KB
  __shared__ u16   wt[128*64];     // 16 KB  [o][k] swizzled
  __shared__ u16   ft[64*64];      //  8 KB  [m][k] swizzled

  int t = threadIdx.x;
  int bx = blockIdx.x;
  int rowtile = bx >> 1, coltile = bx & 1;
  int brow = rowtile * 64;

  for (int i = t; i < 6*NN; i += 512) subq[i] = ws[WS_SUBQ + i];

  // normed for this block's 64 rows, kept in registers:
  // thread t owns row m = t>>3, n-groups n = j*64 + (t&7)*8 .. +8, j=0..7
  int m = t >> 3, lane8 = t & 7;
  uint32 nreg[32];
  {
    const float* xrow = x + (size_t)(brow + m)*NN;
    #pragma unroll
    for (int j=0; j<8; ++j){
      int n0 = j*64 + lane8*8;
      float4 a  = *(const float4*)(xrow + n0);
      float4 b  = *(const float4*)(xrow + n0 + 4);
      float4 sa = *(const float4*)(ws + WS_SCALE + n0);
      float4 sb = *(const float4*)(ws + WS_SCALE + n0 + 4);
      float4 ha = *(const float4*)(ws + WS_SHIFT + n0);
      float4 hb = *(const float4*)(ws + WS_SHIFT + n0 + 4);
      nreg[j*4+0] = pk2(fmaf(a.x,sa.x,ha.x), fmaf(a.y,sa.y,ha.y));
      nreg[j*4+1] = pk2(fmaf(a.z,sa.z,ha.z), fmaf(a.w,sa.w,ha.w));
      nreg[j*4+2] = pk2(fmaf(b.x,sb.x,hb.x), fmaf(b.y,sb.y,hb.y));
      nreg[j*4+3] = pk2(fmaf(b.z,sb.z,hb.z), fmaf(b.w,sb.w,hb.w));
    }
  }
  __syncthreads();   // subq ready

  f32x4 acc[2][2] = {};
  int wv = t >> 6, lane = t & 63;
  int wm = wv >> 2, wn = wv & 3;
  int lr = lane & 15, lk = lane >> 4;
  int ftdst = m*64 + ((lane8 ^ (m&7))*8);   // swizzled slot for this thread's 8 k-values

  for (int c=0; c<64; ++c){
    // ---- stage W tile (16 KB, swizzle pre-baked in wrT, linear copy) ----
    {
      const u16* wsrc = wrT + c*16384 + coltile*8192;
      bf16x8 w0 = *(const bf16x8*)(wsrc + t*8);
      bf16x8 w1 = *(const bf16x8*)(wsrc + 4096 + t*8);
      *(bf16x8*)(wt + t*8) = w0;
      *(bf16x8*)(wt + 4096 + t*8) = w1;
    }
    // ---- stage feat tile (64x64) ----
    if (c < 48){
      int j = c & 7, q = c >> 3;
      int n0 = j*64 + lane8*8;
      const float* sq = subq + q*NN + n0;
      float4 s0 = *(const float4*)sq;
      float4 s1 = *(const float4*)(sq + 4);
      uint32 p0=nreg[4*j], p1=nreg[4*j+1], p2=nreg[4*j+2], p3=nreg[4*j+3];
      union { bf16x8 v; uint32 u[4]; } R;
      R.u[0] = pk2(fmaxf(plo(p0)-s0.x,0.f), fmaxf(phi(p0)-s0.y,0.f));
      R.u[1] = pk2(fmaxf(plo(p1)-s0.z,0.f), fmaxf(phi(p1)-s0.w,0.f));
      R.u[2] = pk2(fmaxf(plo(p2)-s1.x,0.f), fmaxf(phi(p2)-s1.y,0.f));
      R.u[3] = pk2(fmaxf(plo(p3)-s1.z,0.f), fmaxf(phi(p3)-s1.w,0.f));
      *(bf16x8*)(ft + ftdst) = R.v;
    } else {
      int cc = c - 48;
      bf16x8 av = *(const bf16x8*)(amin + (size_t)(brow + m)*1024 + cc*64 + lane8*8);
      *(bf16x8*)(ft + ftdst) = av;
    }
    __syncthreads();

    // ---- MFMA: 2 k-subs of 32, acc[2][2] of 16x16 ----
    #pragma unroll
    for (int ks=0; ks<2; ++ks){
      int kg = ks*4 + lk;
      bf16x8 af[2], bfr[2];
      #pragma unroll
      for (int mi=0; mi<2; ++mi){
        int row = wm*32 + mi*16 + lr;
        af[mi] = *(const bf16x8*)(ft + row*64 + ((kg ^ (row&7))*8));
      }
      #pragma unroll
      for (int ni=0; ni<2; ++ni){
        int o = wn*32 + ni*16 + lr;
        bfr[ni] = *(const bf16x8*)(wt + o*64 + ((kg ^ (o&7))*8));
      }
      #pragma unroll
      for (int mi=0; mi<2; ++mi)
        #pragma unroll
        for (int ni=0; ni<2; ++ni)
          acc[mi][ni] = __builtin_amdgcn_mfma_f32_16x16x32_bf16(af[mi], bfr[ni], acc[mi][ni], 0, 0, 0);
    }
    __syncthreads();
  }

  // ---- epilogue ----
  float bias = biases[0];
  #pragma unroll
  for (int mi=0; mi<2; ++mi)
    #pragma unroll
    for (int ni=0; ni<2; ++ni)
      #pragma unroll
      for (int r=0; r<4; ++r){
        int row = brow + wm*32 + mi*16 + lk*4 + r;
        int col = coltile*128 + wn*32 + ni*16 + lr;
        out[(size_t)row*ON + col] = acc[mi][ni][r] + bias;
      }
}

extern "C" void kernel_launch(void* const* d_in, const int* in_sizes, int n_in,
                              void* d_out, int out_size, void* d_ws, size_t ws_size,
                              hipStream_t stream){
  const float* x      = (const float*)d_in[0];
  const float* beta   = (const float*)d_in[1];
  const float* gamma  = (const float*)d_in[2];
  const float* w      = (const float*)d_in[3];
  const float* biases = (const float*)d_in[4];
  const int*   ci     = (const int*)d_in[5];
  float* out = (float*)d_out;
  float* wsf = (float*)d_ws;
  u16* wrT  = (u16*)((char*)d_ws + WRT_OFF);
  u16* amin = (u16*)((char*)d_ws + AMIN_OFF);

  k_stats_partial<<<128, 512, 0, stream>>>(x, wsf);
  k_stats_final  <<<1,   512, 0, stream>>>(beta, gamma, wsf);
  k_prep_w       <<<64,  256, 0, stream>>>(w, wrT);
  k_minfeat      <<<8192,256, 0, stream>>>(x, wsf, ci, amin);
  k_gemm         <<<256, 512, 0, stream>>>(x, wsf, wrT, amin, biases, out);
}

// Round 2
// 75.015 us; speedup vs baseline: 1.6334x; 1.6334x over previous
//
#include <hip/hip_runtime.h>
#include <stdint.h>

typedef unsigned int uint32;
typedef unsigned short u16;
typedef __attribute__((ext_vector_type(8))) short bf16x8;
typedef __attribute__((ext_vector_type(4))) float f32x4;

// ws float-offsets
#define WS_SCALE 0
#define WS_SHIFT 512
#define WS_SUBQ  1024            // 6*512 (sub[0]=0)
#define WS_SHSUB 4096            // 6*512 (shift - sub[q])
#define WS_PSUM  8192            // 128*512
#define WS_PSQ   (8192+65536)
// ws byte offsets
#define WRT_OFF  (1u<<20)        // 64 chunks * 16384 u16 = 2 MB
#define AMIN_OFF (3u<<20)        // 8192*1024 bf16 = 16 MB (pre-swizzled rows)
#define PART_OFF (19u<<20)       // 4*8192*256 bf16 = 16 MB

__device__ __forceinline__ u16 f2bf(float f){
  uint32 u; __builtin_memcpy(&u,&f,4);
  u = u + 0x7fffu + ((u>>16)&1u);
  return (u16)(u>>16);
}
__device__ __forceinline__ float bf2f(u16 b){
  uint32 u = ((uint32)b)<<16; float f; __builtin_memcpy(&f,&u,4); return f;
}
__device__ __forceinline__ uint32 pk2(float a, float b){
  return (uint32)f2bf(a) | ((uint32)f2bf(b)<<16);
}
__device__ __forceinline__ void gll16(u16* lds, const u16* g){
  __builtin_amdgcn_global_load_lds((const __attribute__((address_space(1))) uint32*)g,
                                   (__attribute__((address_space(3))) uint32*)lds, 16, 0, 0);
}

// ---------------- stats: partial column sums ----------------
__global__ __launch_bounds__(512) void k_stats_partial(const float* __restrict__ x,
                                                       float* __restrict__ ws){
  int s = blockIdx.x;          // 128 blocks, 64 rows each
  int n = threadIdx.x;         // 512 threads = columns
  const float* xp = x + (size_t)s*64*512 + n;
  float sum = 0.f, sq = 0.f;
  #pragma unroll 8
  for (int r=0; r<64; ++r){ float v = xp[(size_t)r*512]; sum += v; sq += v*v; }
  ws[WS_PSUM + s*512 + n] = sum;
  ws[WS_PSQ  + s*512 + n] = sq;
}

// ---------------- stats: finalize ----------------
__global__ __launch_bounds__(512) void k_stats_final(const float* __restrict__ beta,
                                                     const float* __restrict__ gamma,
                                                     float* __restrict__ ws){
  int n = threadIdx.x;
  float sum = 0.f, sq = 0.f;
  for (int s=0; s<128; ++s){ sum += ws[WS_PSUM + s*512 + n]; sq += ws[WS_PSQ + s*512 + n]; }
  float mean = sum * (1.0f/8192.0f);
  float var  = sq  * (1.0f/8192.0f) - mean*mean;
  float g = gamma[n], b = beta[n];
  float inv = 1.0f / sqrtf(var + 0.001f);
  float scale = g * inv;
  float shift = b - mean*scale;
  ws[WS_SCALE + n] = scale;
  ws[WS_SHIFT + n] = shift;
  const float QC[5] = {-3.0f, -0.834f, -0.248f, 0.248f, 0.834f};
  ws[WS_SUBQ  + n] = 0.f;
  ws[WS_SHSUB + n] = shift;
  #pragma unroll
  for (int c=0; c<5; ++c){
    float sub = (QC[c]*var + mean)*g - b;
    ws[WS_SUBQ  + (c+1)*512 + n] = sub;
    ws[WS_SHSUB + (c+1)*512 + n] = shift - sub;
  }
}

// ---------------- w reorder: chunk c covers k'=c*64.. (k'=q*512+n then min rows); [o][swizzled k] bf16 ----------------
__global__ __launch_bounds__(256) void k_prep_w(const float* __restrict__ w,
                                                u16* __restrict__ wrT){
  int c = blockIdx.x;          // 64 K-chunks of 64
  int o = threadIdx.x;         // 256 output cols
  int swz = o & 7;
  u16* dst = wrT + c*16384 + o*64;
  #pragma unroll
  for (int g=0; g<8; ++g){
    union { bf16x8 v; u16 h[8]; } R;
    #pragma unroll
    for (int i=0; i<8; ++i){
      int k = g*8 + i;
      int sk;
      if (c < 48){ int q = c>>3; int n = (c&7)*64 + k; sk = n*6 + q; }
      else       { sk = 3072 + (c-48)*64 + k; }
      R.h[i] = f2bf(w[(size_t)sk*256 + o]);
    }
    *(bf16x8*)(dst + ((g ^ swz)*8)) = R.v;
  }
}

// ---------------- min-feature matrix A'' (8192 x 1024 bf16, pre-swizzled per row&7) ----------------
__global__ __launch_bounds__(256) void k_minfeat(const float* __restrict__ x,
                                                 const float* __restrict__ ws,
                                                 const int* __restrict__ ci,
                                                 u16* __restrict__ amin){
  __shared__ float nrm[8][512];     // 16 KB
  __shared__ uint32 tnn[1024];      // n1 | n2<<16
  __shared__ float ts1[1024];
  __shared__ float ts2[1024];
  int t = threadIdx.x;
  int b0 = blockIdx.x * 8;
  #pragma unroll
  for (int ii=0; ii<4; ++ii){
    int i = ii*256 + t;
    int n1 = ci[i*5+1], q1 = ci[i*5+2], n2 = ci[i*5+3], q2 = ci[i*5+4];
    tnn[i] = (uint32)n1 | ((uint32)n2 << 16);
    ts1[i] = ws[WS_SUBQ + q1*512 + n1];
    ts2[i] = ws[WS_SUBQ + q2*512 + n2];
  }
  {
    int r = t >> 5, c0 = (t & 31) * 16;
    const float* xr = x + (size_t)(b0 + r)*512 + c0;
    #pragma unroll
    for (int j=0;j<4;++j){
      float4 v  = *(const float4*)(xr + j*4);
      float4 sc = *(const float4*)(ws + WS_SCALE + c0 + j*4);
      float4 sh = *(const float4*)(ws + WS_SHIFT + c0 + j*4);
      float4 o; o.x=fmaf(v.x,sc.x,sh.x); o.y=fmaf(v.y,sc.y,sh.y);
      o.z=fmaf(v.z,sc.z,sh.z); o.w=fmaf(v.w,sc.w,sh.w);
      *(float4*)(&nrm[r][c0+j*4]) = o;
    }
  }
  __syncthreads();
  int m0 = t*4;
  uint4  nn = *(const uint4*)(&tnn[m0]);
  float4 s1 = *(const float4*)(&ts1[m0]);
  float4 s2 = *(const float4*)(&ts2[m0]);
  int cc = m0 >> 6, k = m0 & 63, g = k >> 3;
  #pragma unroll
  for (int r=0;r<8;++r){
    float v0 = fminf(fmaxf(nrm[r][nn.x & 0xffff] - s1.x, 0.f), fmaxf(nrm[r][nn.x >> 16] - s2.x, 0.f));
    float v1 = fminf(fmaxf(nrm[r][nn.y & 0xffff] - s1.y, 0.f), fmaxf(nrm[r][nn.y >> 16] - s2.y, 0.f));
    float v2 = fminf(fmaxf(nrm[r][nn.z & 0xffff] - s1.z, 0.f), fmaxf(nrm[r][nn.z >> 16] - s2.z, 0.f));
    float v3 = fminf(fmaxf(nrm[r][nn.w & 0xffff] - s1.w, 0.f), fmaxf(nrm[r][nn.w >> 16] - s2.w, 0.f));
    int pos = cc*64 + ((g ^ r)*8) + (k & 7);
    uint2 pv; pv.x = pk2(v0,v1); pv.y = pk2(v2,v3);
    *(uint2*)(amin + (size_t)(b0 + r)*1024 + pos) = pv;
  }
}

// ---------------- split-K fused feature-GEMM ----------------
// 256 blocks: mtile (64, BM=128) x ksplit s (4, K=1024 each). BN=256 full. 512 thr = 8 waves (2Mx4N),
// wave tile 64x64, acc[4][4] 16x16x32 MFMA. Double-buffered LDS, global_load_lds for W (+amin, split 3).
__global__ __launch_bounds__(512) void k_gemm(const float* __restrict__ x,
                                              const float* __restrict__ ws,
                                              const u16* __restrict__ wrT,
                                              const u16* __restrict__ amin,
                                              u16* __restrict__ parts){
  extern __shared__ u16 smem[];
  u16* wt = smem;                         // [2][16384]  256x64 swizzled
  u16* ft = smem + 32768;                 // [2][8192]   128x64 swizzled
  float* pscale = (float*)(smem + 49152); // 512
  float* pshsub = pscale + 512;           // [2][512]

  int t = threadIdx.x;
  int d = blockIdx.x;
  int mtile = (d & 7) * 8 + ((d >> 3) >> 2);   // co-XCD: same mtile's 4 splits share an XCD's L2
  int s = (d >> 3) & 3;
  int brow = mtile * 128;

  if (s < 3){
    pscale[t & 511] = ws[WS_SCALE + (t & 511)];
    pshsub[t]       = ws[WS_SHSUB + (2*s)*512 + t % 512 + (t >> 9)*512];
  }
  // fix param load simply: thread t<512 loads pscale[t], pshsub rows via two stores
  if (s < 3){
    pshsub[t]       = ws[WS_SHSUB + (2*s)*512 + t];       // t in [0,512) -> row 2s ... [512,1024) handled below
  }
  if (s < 3 && t < 512){
    pshsub[512 + t] = ws[WS_SHSUB + (2*s+1)*512 + t];
  }

  const int row0 = t >> 3, gc = t & 7;
  const int wuni = t & ~63;
  const int ftswz = (gc ^ (row0 & 7)) * 8;

  auto stage = [&](int cc, int nb){
    u16* wtb = wt + nb * 16384;
    u16* ftb = ft + nb * 8192;
    const u16* wsrc = wrT + (size_t)(s*16 + cc) * 16384;
    if (s < 3){
      int q = cc >> 3, n0 = (cc & 7) * 64;
      int col = n0 + gc * 8;
      const float* xp = x + (size_t)(brow + row0) * 512 + col;
      float4 xa0 = *(const float4*)xp;
      float4 xa1 = *(const float4*)(xp + 4);
      float4 xb0 = *(const float4*)(xp + 64*512);
      float4 xb1 = *(const float4*)(xp + 64*512 + 4);
      #pragma unroll
      for (int r2 = 0; r2 < 4; ++r2)
        gll16(wtb + (size_t)(r2*512 + wuni)*8, wsrc + (size_t)(r2*512 + t)*8);
      float4 sc0 = *(const float4*)(pscale + col);
      float4 sc1 = *(const float4*)(pscale + col + 4);
      const float* hb = pshsub + q*512 + col;
      float4 hh0 = *(const float4*)hb;
      float4 hh1 = *(const float4*)(hb + 4);
      union { bf16x8 v; uint32 u[4]; } Ra, Rb;
      Ra.u[0] = pk2(fmaxf(fmaf(xa0.x,sc0.x,hh0.x),0.f), fmaxf(fmaf(xa0.y,sc0.y,hh0.y),0.f));
      Ra.u[1] = pk2(fmaxf(fmaf(xa0.z,sc0.z,hh0.z),0.f), fmaxf(fmaf(xa0.w,sc0.w,hh0.w),0.f));
      Ra.u[2] = pk2(fmaxf(fmaf(xa1.x,sc1.x,hh1.x),0.f), fmaxf(fmaf(xa1.y,sc1.y,hh1.y),0.f));
      Ra.u[3] = pk2(fmaxf(fmaf(xa1.z,sc1.z,hh1.z),0.f), fmaxf(fmaf(xa1.w,sc1.w,hh1.w),0.f));
      Rb.u[0] = pk2(fmaxf(fmaf(xb0.x,sc0.x,hh0.x),0.f), fmaxf(fmaf(xb0.y,sc0.y,hh0.y),0.f));
      Rb.u[1] = pk2(fmaxf(fmaf(xb0.z,sc0.z,hh0.z),0.f), fmaxf(fmaf(xb0.w,sc0.w,hh0.w),0.f));
      Rb.u[2] = pk2(fmaxf(fmaf(xb1.x,sc1.x,hh1.x),0.f), fmaxf(fmaf(xb1.y,sc1.y,hh1.y),0.f));
      Rb.u[3] = pk2(fmaxf(fmaf(xb1.z,sc1.z,hh1.z),0.f), fmaxf(fmaf(xb1.w,sc1.w,hh1.w),0.f));
      *(bf16x8*)(ftb + row0*64 + ftswz) = Ra.v;
      *(bf16x8*)(ftb + (row0+64)*64 + ftswz) = Rb.v;
    } else {
      #pragma unroll
      for (int r2 = 0; r2 < 4; ++r2)
        gll16(wtb + (size_t)(r2*512 + wuni)*8, wsrc + (size_t)(r2*512 + t)*8);
      #pragma unroll
      for (int r2 = 0; r2 < 2; ++r2){
        int e = r2*512 + t;
        gll16(ftb + (size_t)(r2*512 + wuni)*8,
              amin + (size_t)(brow + (e>>3))*1024 + cc*64 + (e&7)*8);
      }
    }
  };

  int lane = t & 63, wv = t >> 6;
  int wm = wv >> 2, wn = wv & 3;
  int lr = lane & 15, lk = lane >> 4, rsw = lr & 7;
  f32x4 acc[4][4] = {};

  auto compute = [&](int cb){
    const u16* ftb = ft + cb*8192;
    const u16* wtb = wt + cb*16384;
    #pragma unroll
    for (int ks=0; ks<2; ++ks){
      int g16 = ((ks*4 + lk) ^ rsw) * 8;
      bf16x8 A[4], Bv[4];
      #pragma unroll
      for (int mi=0; mi<4; ++mi)
        A[mi] = *(const bf16x8*)(ftb + (wm*64 + mi*16 + lr)*64 + g16);
      #pragma unroll
      for (int ni=0; ni<4; ++ni)
        Bv[ni] = *(const bf16x8*)(wtb + (wn*64 + ni*16 + lr)*64 + g16);
      #pragma unroll
      for (int mi=0; mi<4; ++mi)
        #pragma unroll
        for (int ni=0; ni<4; ++ni)
          acc[mi][ni] = __builtin_amdgcn_mfma_f32_16x16x32_bf16(A[mi], Bv[ni], acc[mi][ni], 0, 0, 0);
    }
  };

  __syncthreads();        // params visible
  stage(0, 0);
  __syncthreads();
  int cur = 0;
  for (int c=0; c<16; ++c){
    if (c < 15) stage(c+1, cur^1);
    compute(cur);
    __syncthreads();
    cur ^= 1;
  }

  u16* pp = parts + ((size_t)s*8192 + brow)*256;
  #pragma unroll
  for (int mi=0; mi<4; ++mi)
    #pragma unroll
    for (int ni=0; ni<4; ++ni)
      #pragma unroll
      for (int r=0; r<4; ++r){
        int rl = wm*64 + mi*16 + lk*4 + r;
        int cl = wn*64 + ni*16 + lr;
        pp[(size_t)rl*256 + cl] = f2bf(acc[mi][ni][r]);
      }
}

// ---------------- reduce 4 bf16 partials + bias ----------------
__global__ __launch_bounds__(256) void k_reduce(const u16* __restrict__ parts,
                                                const float* __restrict__ biases,
                                                float* __restrict__ out){
  int i = (blockIdx.x*256 + threadIdx.x) * 8;
  float b = biases[0];
  float a[8];
  #pragma unroll
  for (int j=0;j<8;++j) a[j] = b;
  #pragma unroll
  for (int s2=0;s2<4;++s2){
    bf16x8 v = *(const bf16x8*)(parts + (size_t)s2*2097152 + i);
    #pragma unroll
    for (int j=0;j<8;++j) a[j] += bf2f((u16)v[j]);
  }
  float4 o0 = {a[0],a[1],a[2],a[3]}, o1 = {a[4],a[5],a[6],a[7]};
  *(float4*)(out + i) = o0;
  *(float4*)(out + i + 4) = o1;
}

extern "C" void kernel_launch(void* const* d_in, const int* in_sizes, int n_in,
                              void* d_out, int out_size, void* d_ws, size_t ws_size,
                              hipStream_t stream){
  const float* x      = (const float*)d_in[0];
  const float* beta   = (const float*)d_in[1];
  const float* gamma  = (const float*)d_in[2];
  const float* w      = (const float*)d_in[3];
  const float* biases = (const float*)d_in[4];
  const int*   ci     = (const int*)d_in[5];
  float* out = (float*)d_out;
  float* wsf = (float*)d_ws;
  u16* wrT   = (u16*)((char*)d_ws + WRT_OFF);
  u16* amin  = (u16*)((char*)d_ws + AMIN_OFF);
  u16* parts = (u16*)((char*)d_ws + PART_OFF);

  hipFuncSetAttribute((const void*)k_gemm, hipFuncAttributeMaxDynamicSharedMemorySize, 104448);

  k_stats_partial<<<128, 512, 0, stream>>>(x, wsf);
  k_stats_final  <<<1,   512, 0, stream>>>(beta, gamma, wsf);
  k_prep_w       <<<64,  256, 0, stream>>>(w, wrT);
  k_minfeat      <<<1024,256, 0, stream>>>(x, wsf, ci, amin);
  k_gemm         <<<256, 512, 104448, stream>>>(x, wsf, wrT, amin, parts);
  k_reduce       <<<1024,256, 0, stream>>>(parts, biases, out);
}

// Round 4
// 61.991 us; speedup vs baseline: 1.9766x; 1.2101x over previous
//
#include <hip/hip_runtime.h>
#include <stdint.h>

typedef unsigned int uint32;
typedef unsigned short u16;
typedef __attribute__((ext_vector_type(8))) short bf16x8;
typedef __attribute__((ext_vector_type(4))) float f32x4;

// ws float-offsets
#define WS_SCALE 0
#define WS_SHIFT 512
#define WS_SUBQ  1024            // 6*512 (sub[0]=0)
#define WS_SHSUB 4096            // 6*512 (shift - sub[q])
#define WS_PSUM  8192            // 128*512
#define WS_PSQ   (8192+65536)
// ws byte offsets
#define WRT_OFF  (1u<<20)        // 128 chunks * 8192 u16 = 2 MB
#define AMIN_OFF (3u<<20)        // 8192*1024 bf16 = 16 MB (pre-swizzled rows)
#define PART_OFF (19u<<20)       // 8*8192*256 bf16 = 32 MB

__device__ __forceinline__ u16 f2bf(float f){
  uint32 u; __builtin_memcpy(&u,&f,4);
  u = u + 0x7fffu + ((u>>16)&1u);
  return (u16)(u>>16);
}
__device__ __forceinline__ float bf2f(u16 b){
  uint32 u = ((uint32)b)<<16; float f; __builtin_memcpy(&f,&u,4); return f;
}
__device__ __forceinline__ uint32 pk2(float a, float b){
  return (uint32)f2bf(a) | ((uint32)f2bf(b)<<16);
}
__device__ __forceinline__ void gll16(u16* lds, const u16* g){
  __builtin_amdgcn_global_load_lds((const __attribute__((address_space(1))) uint32*)g,
                                   (__attribute__((address_space(3))) uint32*)lds, 16, 0, 0);
}

// ---------------- fused: stats partials (blocks 0..127) + w reorder (blocks 128..255) ----------------
// wrT layout: 128 chunks of 32 k' (k' = q*512+n for k'<3072, then min rows).
// chunk c2: [o][32] u16, 16B-slot position = (g ^ ((o>>1)&3)), g = k>>3.
__global__ __launch_bounds__(512) void k_pre(const float* __restrict__ x,
                                             const float* __restrict__ w,
                                             float* __restrict__ ws,
                                             u16* __restrict__ wrT){
  int b = blockIdx.x, t = threadIdx.x;
  if (b < 128){
    const float* xp = x + (size_t)b*64*512 + t;
    float sum = 0.f, sq = 0.f;
    #pragma unroll 8
    for (int r=0; r<64; ++r){ float v = xp[(size_t)r*512]; sum += v; sq += v*v; }
    ws[WS_PSUM + b*512 + t] = sum;
    ws[WS_PSQ  + b*512 + t] = sq;
  } else {
    int c2 = b - 128;            // 0..127
    int o = t & 255, half = t >> 8;
    int swzrow = (o >> 1) & 3;
    u16* dst = wrT + (size_t)c2*8192 + o*32;
    #pragma unroll
    for (int gi=0; gi<2; ++gi){
      int g = half*2 + gi;
      union { bf16x8 v; u16 h[8]; } R;
      #pragma unroll
      for (int e=0; e<8; ++e){
        int k = g*8 + e;
        int sk;
        if (c2 < 96) sk = ((c2 & 15)*32 + k)*6 + (c2 >> 4);
        else         sk = 3072 + (c2 - 96)*32 + k;
        R.h[e] = f2bf(w[(size_t)sk*256 + o]);
      }
      *(bf16x8*)(dst + ((g ^ swzrow)*8)) = R.v;
    }
  }
}

// ---------------- stats: finalize ----------------
__global__ __launch_bounds__(512) void k_stats_final(const float* __restrict__ beta,
                                                     const float* __restrict__ gamma,
                                                     float* __restrict__ ws){
  int n = threadIdx.x;
  float sum = 0.f, sq = 0.f;
  #pragma unroll 8
  for (int s2=0; s2<128; ++s2){ sum += ws[WS_PSUM + s2*512 + n]; sq += ws[WS_PSQ + s2*512 + n]; }
  float mean = sum * (1.0f/8192.0f);
  float var  = sq  * (1.0f/8192.0f) - mean*mean;
  float g = gamma[n], b = beta[n];
  float inv = 1.0f / sqrtf(var + 0.001f);
  float scale = g * inv;
  float shift = b - mean*scale;
  ws[WS_SCALE + n] = scale;
  ws[WS_SHIFT + n] = shift;
  const float QC[5] = {-3.0f, -0.834f, -0.248f, 0.248f, 0.834f};
  ws[WS_SUBQ  + n] = 0.f;
  ws[WS_SHSUB + n] = shift;
  #pragma unroll
  for (int c=0; c<5; ++c){
    float sub = (QC[c]*var + mean)*g - b;
    ws[WS_SUBQ  + (c+1)*512 + n] = sub;
    ws[WS_SHSUB + (c+1)*512 + n] = shift - sub;
  }
}

// ---------------- min-feature matrix A'' (8192 x 1024 bf16, rows pre-swizzled per 32-col chunk) ----------------
__global__ __launch_bounds__(256) void k_minfeat(const float* __restrict__ x,
                                                 const float* __restrict__ ws,
                                                 const int* __restrict__ ci,
                                                 u16* __restrict__ amin){
  __shared__ float nrm[8][512];     // 16 KB
  __shared__ uint32 tnn[1024];      // n1 | n2<<16
  __shared__ float ts1[1024];
  __shared__ float ts2[1024];
  int t = threadIdx.x;
  int b0 = blockIdx.x * 8;
  #pragma unroll
  for (int ii=0; ii<4; ++ii){
    int i = ii*256 + t;
    int n1 = ci[i*5+1], q1 = ci[i*5+2], n2 = ci[i*5+3], q2 = ci[i*5+4];
    tnn[i] = (uint32)n1 | ((uint32)n2 << 16);
    ts1[i] = ws[WS_SUBQ + q1*512 + n1];
    ts2[i] = ws[WS_SUBQ + q2*512 + n2];
  }
  {
    int r = t >> 5, c0 = (t & 31) * 16;
    const float* xr = x + (size_t)(b0 + r)*512 + c0;
    #pragma unroll
    for (int j=0;j<4;++j){
      float4 v  = *(const float4*)(xr + j*4);
      float4 sc = *(const float4*)(ws + WS_SCALE + c0 + j*4);
      float4 sh = *(const float4*)(ws + WS_SHIFT + c0 + j*4);
      float4 o; o.x=fmaf(v.x,sc.x,sh.x); o.y=fmaf(v.y,sc.y,sh.y);
      o.z=fmaf(v.z,sc.z,sh.z); o.w=fmaf(v.w,sc.w,sh.w);
      *(float4*)(&nrm[r][c0+j*4]) = o;
    }
  }
  __syncthreads();
  int m0 = t*4;
  uint4  nn = *(const uint4*)(&tnn[m0]);
  float4 s1 = *(const float4*)(&ts1[m0]);
  float4 s2 = *(const float4*)(&ts2[m0]);
  int cc = m0 >> 5, k = m0 & 31, g2 = k >> 3;
  #pragma unroll
  for (int r=0;r<8;++r){
    float v0 = fminf(fmaxf(nrm[r][nn.x & 0xffff] - s1.x, 0.f), fmaxf(nrm[r][nn.x >> 16] - s2.x, 0.f));
    float v1 = fminf(fmaxf(nrm[r][nn.y & 0xffff] - s1.y, 0.f), fmaxf(nrm[r][nn.y >> 16] - s2.y, 0.f));
    float v2 = fminf(fmaxf(nrm[r][nn.z & 0xffff] - s1.z, 0.f), fmaxf(nrm[r][nn.z >> 16] - s2.z, 0.f));
    float v3 = fminf(fmaxf(nrm[r][nn.w & 0xffff] - s1.w, 0.f), fmaxf(nrm[r][nn.w >> 16] - s2.w, 0.f));
    int pos = cc*32 + ((g2 ^ (((b0 + r) >> 1) & 3))*8) + (k & 7);
    uint2 pv; pv.x = pk2(v0,v1); pv.y = pk2(v2,v3);
    *(uint2*)(amin + (size_t)(b0 + r)*1024 + pos) = pv;
  }
}

// ---------------- split-K=8 fused feature-GEMM ----------------
// 512 blocks: d = s*64 + mtile  (XCD = d%8 = mtile%8 -> all 8 splits of a mtile co-XCD).
// BM=128, BN=256, BK=32, 16 chunks/block. 512 thr = 8 waves (2Mx4N), wave tile 64x64,
// acc[4][4] 16x16x32 MFMA. Double-buffered 53KB static LDS -> 2 blocks/CU.
__global__ __launch_bounds__(512,4) void k_gemm(const float* __restrict__ x,
                                                const float* __restrict__ ws,
                                                const u16* __restrict__ wrT,
                                                const u16* __restrict__ amin,
                                                u16* __restrict__ parts){
  __shared__ u16 wt[2][8192];      // 32 KB  [o][32] swizzled
  __shared__ u16 ft[2][4096];      // 16 KB  [m][32] swizzled
  __shared__ float pscale[512];
  __shared__ float pshsub[512];

  int t = threadIdx.x;
  int d = blockIdx.x;
  int mtile = d & 63, s = d >> 6;
  int brow = mtile * 128;
  bool isMin = (s >= 6);

  if (!isMin){
    pscale[t] = ws[WS_SCALE + t];
    pshsub[t] = ws[WS_SHSUB + s*512 + t];
  }

  int row = t >> 2, g = t & 3;
  int ftw = row*32 + ((g ^ ((row >> 1) & 3))*8);
  int wuni = t & ~63;
  const float* xrow = x + (size_t)(brow + row)*512;
  const u16* aminrow = amin + (size_t)(brow + row)*1024 + (isMin ? (s-6)*512 : 0) + g*8;
  const u16* wbase = wrT + (size_t)(s*16)*8192;

  int lane = t & 63, wv = t >> 6;
  int wm = wv >> 2, wn = wv & 3;
  int lr = lane & 15, lk = lane >> 4;
  int g16 = (lk ^ ((lr >> 1) & 3)) * 8;
  f32x4 acc[4][4] = {};

  __syncthreads();   // params visible

  auto stage = [&](int cc, int nb){
    const u16* wsrc = wbase + (size_t)cc*8192;
    gll16(&wt[nb][wuni*8], wsrc + (size_t)t*8);
    gll16(&wt[nb][4096 + wuni*8], wsrc + 4096 + (size_t)t*8);
    if (!isMin){
      int col = cc*32 + g*8;
      float4 a0  = *(const float4*)(xrow + col);
      float4 a1  = *(const float4*)(xrow + col + 4);
      float4 sc0 = *(const float4*)(pscale + col);
      float4 sc1 = *(const float4*)(pscale + col + 4);
      float4 h0  = *(const float4*)(pshsub + col);
      float4 h1  = *(const float4*)(pshsub + col + 4);
      union { bf16x8 v; uint32 u[4]; } R;
      R.u[0] = pk2(fmaxf(fmaf(a0.x,sc0.x,h0.x),0.f), fmaxf(fmaf(a0.y,sc0.y,h0.y),0.f));
      R.u[1] = pk2(fmaxf(fmaf(a0.z,sc0.z,h0.z),0.f), fmaxf(fmaf(a0.w,sc0.w,h0.w),0.f));
      R.u[2] = pk2(fmaxf(fmaf(a1.x,sc1.x,h1.x),0.f), fmaxf(fmaf(a1.y,sc1.y,h1.y),0.f));
      R.u[3] = pk2(fmaxf(fmaf(a1.z,sc1.z,h1.z),0.f), fmaxf(fmaf(a1.w,sc1.w,h1.w),0.f));
      *(bf16x8*)(&ft[nb][ftw]) = R.v;
    } else {
      gll16(&ft[nb][wuni*8], aminrow + cc*32);
    }
  };

  auto compute = [&](int cb){
    bf16x8 A[4], Bv[4];
    #pragma unroll
    for (int mi=0; mi<4; ++mi)
      A[mi] = *(const bf16x8*)(&ft[cb][(wm*64 + mi*16 + lr)*32 + g16]);
    #pragma unroll
    for (int ni=0; ni<4; ++ni)
      Bv[ni] = *(const bf16x8*)(&wt[cb][(wn*64 + ni*16 + lr)*32 + g16]);
    #pragma unroll
    for (int mi=0; mi<4; ++mi)
      #pragma unroll
      for (int ni=0; ni<4; ++ni)
        acc[mi][ni] = __builtin_amdgcn_mfma_f32_16x16x32_bf16(A[mi], Bv[ni], acc[mi][ni], 0, 0, 0);
  };

  stage(0, 0);
  __syncthreads();
  int cur = 0;
  for (int c=0; c<16; ++c){
    if (c < 15) stage(c+1, cur^1);
    compute(cur);
    __syncthreads();
    cur ^= 1;
  }

  u16* pp = parts + ((size_t)s*8192 + brow)*256;
  #pragma unroll
  for (int mi=0; mi<4; ++mi)
    #pragma unroll
    for (int ni=0; ni<4; ++ni)
      #pragma unroll
      for (int r=0; r<4; ++r){
        int rl = wm*64 + mi*16 + lk*4 + r;
        int cl = wn*64 + ni*16 + lr;
        pp[(size_t)rl*256 + cl] = f2bf(acc[mi][ni][r]);
      }
}

// ---------------- reduce 8 bf16 partials + bias ----------------
__global__ __launch_bounds__(256) void k_reduce(const u16* __restrict__ parts,
                                                const float* __restrict__ biases,
                                                float* __restrict__ out){
  int i = (blockIdx.x*256 + threadIdx.x) * 8;
  float b = biases[0];
  float a[8];
  #pragma unroll
  for (int j=0;j<8;++j) a[j] = b;
  #pragma unroll
  for (int s2=0;s2<8;++s2){
    bf16x8 v = *(const bf16x8*)(parts + (size_t)s2*2097152 + i);
    #pragma unroll
    for (int j=0;j<8;++j) a[j] += bf2f((u16)v[j]);
  }
  float4 o0 = {a[0],a[1],a[2],a[3]}, o1 = {a[4],a[5],a[6],a[7]};
  *(float4*)(out + i) = o0;
  *(float4*)(out + i + 4) = o1;
}

extern "C" void kernel_launch(void* const* d_in, const int* in_sizes, int n_in,
                              void* d_out, int out_size, void* d_ws, size_t ws_size,
                              hipStream_t stream){
  const float* x      = (const float*)d_in[0];
  const float* beta   = (const float*)d_in[1];
  const float* gamma  = (const float*)d_in[2];
  const float* w      = (const float*)d_in[3];
  const float* biases = (const float*)d_in[4];
  const int*   ci     = (const int*)d_in[5];
  float* out = (float*)d_out;
  float* wsf = (float*)d_ws;
  u16* wrT   = (u16*)((char*)d_ws + WRT_OFF);
  u16* amin  = (u16*)((char*)d_ws + AMIN_OFF);
  u16* parts = (u16*)((char*)d_ws + PART_OFF);

  k_pre         <<<256, 512, 0, stream>>>(x, w, wsf, wrT);
  k_stats_final <<<1,   512, 0, stream>>>(beta, gamma, wsf);
  k_minfeat     <<<1024,256, 0, stream>>>(x, wsf, ci, amin);
  k_gemm        <<<512, 512, 0, stream>>>(x, wsf, wrT, amin, parts);
  k_reduce      <<<1024,256, 0, stream>>>(parts, biases, out);
}